// Round 1
// baseline (50.055 us; speedup 1.0000x reference)
//
#include <hip/hip_runtime.h>

// BPR-style pairwise ranking loss.
// loss = -sum_b sum_{i<j} log_sigmoid((p_i-p_j)(t_i-t_j)) * (t_i-t_j)^2 * m_i * m_j
// Term is symmetric in (i,j) and zero on the diagonal, so:
// loss = -0.5 * sum_b sum_{i,j} term(i,j)

#define BATCH 1024
#define LEN   256

__global__ __launch_bounds__(256) void bpr_partial_kernel(
    const float* __restrict__ preds,
    const int*   __restrict__ targets,
    const int*   __restrict__ mask,
    float*       __restrict__ partial)
{
    __shared__ float sp[LEN];
    __shared__ float st[LEN];
    __shared__ float sm[LEN];

    const int b = blockIdx.x;
    const int i = threadIdx.x;
    const int base = b * LEN;

    sp[i] = preds[base + i];
    st[i] = (float)targets[base + i];
    sm[i] = (float)mask[base + i];
    __syncthreads();

    const float pi = sp[i];
    const float ti = st[i];
    const float mi = sm[i];

    float acc = 0.0f;
    // j is wave-uniform -> LDS reads are broadcasts (conflict-free).
    #pragma unroll 4
    for (int j = 0; j < LEN; ++j) {
        const float td = ti - st[j];               // in {-1, 0, 1}
        const float w  = td * td * mi * sm[j];     // in {0, 1}
        const float x  = (pi - sp[j]) * td;
        // stable log_sigmoid(x) = min(x,0) - log(1 + exp(-|x|))
        const float xn = fminf(x, 0.0f);
        const float e  = __expf(-fabsf(x));
        const float ls = xn - __logf(1.0f + e);
        acc = fmaf(w, ls, acc);
    }

    // wave (64-lane) reduction
    for (int off = 32; off > 0; off >>= 1)
        acc += __shfl_down(acc, off, 64);

    __shared__ float wpart[4];
    const int wid  = i >> 6;
    const int lane = i & 63;
    if (lane == 0) wpart[wid] = acc;
    __syncthreads();
    if (i == 0)
        partial[b] = wpart[0] + wpart[1] + wpart[2] + wpart[3];
}

__global__ __launch_bounds__(256) void bpr_reduce_kernel(
    const float* __restrict__ partial,
    float*       __restrict__ out)
{
    const int i = threadIdx.x;
    float acc = 0.0f;
    #pragma unroll
    for (int k = i; k < BATCH; k += 256)
        acc += partial[k];

    for (int off = 32; off > 0; off >>= 1)
        acc += __shfl_down(acc, off, 64);

    __shared__ float wpart[4];
    if ((i & 63) == 0) wpart[i >> 6] = acc;
    __syncthreads();
    if (i == 0)
        out[0] = -0.5f * (wpart[0] + wpart[1] + wpart[2] + wpart[3]);
}

extern "C" void kernel_launch(void* const* d_in, const int* in_sizes, int n_in,
                              void* d_out, int out_size, void* d_ws, size_t ws_size,
                              hipStream_t stream) {
    const float* preds   = (const float*)d_in[0];
    const int*   targets = (const int*)d_in[1];
    const int*   mask    = (const int*)d_in[2];
    float* out     = (float*)d_out;
    float* partial = (float*)d_ws;   // BATCH floats of scratch

    bpr_partial_kernel<<<BATCH, 256, 0, stream>>>(preds, targets, mask, partial);
    bpr_reduce_kernel<<<1, 256, 0, stream>>>(partial, out);
}

// Round 2
// 12.207 us; speedup vs baseline: 4.1006x; 4.1006x over previous
//
#include <hip/hip_runtime.h>

// BPR-style pairwise ranking loss.
// loss = -sum_b sum_{i<j} log_sigmoid((p_i-p_j)(t_i-t_j)) * (t_i-t_j)^2 * m_i*m_j
// With t in {0,1}: only (valid-pos, valid-neg) pairs contribute, each unordered
// pair exactly once, with term log_sigmoid(p_pos - p_neg). So per row:
//   loss_b = -sum_{i in P} sum_{j in N} log_sigmoid(p_i - p_j)
// Base-2 form: log_sigmoid(x) = ln2 * (min(y,0) - log2(1 + 2^-|y|)), y = x*log2e.

#define BATCH 1024
#define LEN   256
#define LN2f   0.6931471805599453f
#define LOG2Ef 1.4426950408889634f

__global__ __launch_bounds__(256) void bpr_partial_kernel(
    const float* __restrict__ preds,
    const int*   __restrict__ targets,
    const int*   __restrict__ mask,
    float*       __restrict__ partial)
{
    __shared__ float spos[LEN];     // positives' preds * log2e (compacted)
    __shared__ float sneg[LEN];     // negatives' preds * log2e (compacted)
    __shared__ int   wcp[4], wcn[4];
    __shared__ float wpart[4];

    const int b    = blockIdx.x;
    const int tid  = threadIdx.x;
    const int wid  = tid >> 6;
    const int lane = tid & 63;

    const float p = preds[b * LEN + tid] * LOG2Ef;
    const int   t = targets[b * LEN + tid];
    const int   m = mask[b * LEN + tid];

    const bool ispos = (m != 0) && (t != 0);
    const bool isneg = (m != 0) && (t == 0);

    const unsigned long long bp = __ballot(ispos);
    const unsigned long long bn = __ballot(isneg);
    if (lane == 0) { wcp[wid] = __popcll(bp); wcn[wid] = __popcll(bn); }
    __syncthreads();

    int opos = 0, oneg = 0;
    for (int w = 0; w < wid; ++w) { opos += wcp[w]; oneg += wcn[w]; }
    const int np = wcp[0] + wcp[1] + wcp[2] + wcp[3];
    const int nn = wcn[0] + wcn[1] + wcn[2] + wcn[3];

    const unsigned long long below = (1ull << lane) - 1ull;
    if (ispos) spos[opos + __popcll(bp & below)] = p;
    if (isneg) sneg[oneg + __popcll(bn & below)] = p;
    __syncthreads();

    // Waves split the negative range (j uniform per wave -> LDS broadcast);
    // lanes stride the positives.
    float acc = 0.0f;
    for (int i = lane; i < np; i += 64) {
        const float yi = spos[i];
        for (int j = wid; j < nn; j += 4) {
            const float y = yi - sneg[j];
            const float e = __builtin_amdgcn_exp2f(-fabsf(y)); // v_exp_f32 -abs
            const float l = __builtin_amdgcn_logf(1.0f + e);   // v_log_f32 (log2)
            acc += fminf(y, 0.0f) - l;
        }
    }

    for (int off = 32; off > 0; off >>= 1)
        acc += __shfl_down(acc, off, 64);
    if (lane == 0) wpart[wid] = acc;
    __syncthreads();
    if (tid == 0)
        partial[b] = wpart[0] + wpart[1] + wpart[2] + wpart[3];
}

__global__ __launch_bounds__(256) void bpr_reduce_kernel(
    const float* __restrict__ partial,
    float*       __restrict__ out)
{
    const int i = threadIdx.x;
    float acc = 0.0f;
    #pragma unroll
    for (int k = i; k < BATCH; k += 256)
        acc += partial[k];

    for (int off = 32; off > 0; off >>= 1)
        acc += __shfl_down(acc, off, 64);

    __shared__ float wpart[4];
    if ((i & 63) == 0) wpart[i >> 6] = acc;
    __syncthreads();
    if (i == 0)
        out[0] = -LN2f * (wpart[0] + wpart[1] + wpart[2] + wpart[3]);
}

extern "C" void kernel_launch(void* const* d_in, const int* in_sizes, int n_in,
                              void* d_out, int out_size, void* d_ws, size_t ws_size,
                              hipStream_t stream) {
    const float* preds   = (const float*)d_in[0];
    const int*   targets = (const int*)d_in[1];
    const int*   mask    = (const int*)d_in[2];
    float* out     = (float*)d_out;
    float* partial = (float*)d_ws;   // BATCH floats of scratch

    bpr_partial_kernel<<<BATCH, 256, 0, stream>>>(preds, targets, mask, partial);
    bpr_reduce_kernel<<<1, 256, 0, stream>>>(partial, out);
}